// Round 1
// baseline (927.973 us; speedup 1.0000x reference)
//
#include <hip/hip_runtime.h>
#include <cmath>

#define NB 4
#define NS 1024
#define ND 1024
#define NH 16
#define NDH 64
#define NKSP 32
#define SCALE 0.125f   // 1/sqrt(64)

// ---------------------------------------------------------------------------
// GEMM: C[M,N] = A[M,K] @ W[N,K]^T + bias[N]   (M=4096, N=K=1024 fixed)
// OUT_MODE 0: row-major (B,S,D) output
// OUT_MODE 1: scatter to (B,H,S,DH):  m=b*S+s, n=h*DH+dh
// 64x64 tile, 256 threads, 4x4 per thread, BK=16, transposed LDS tiles.
// ---------------------------------------------------------------------------
template<int OUT_MODE>
__global__ __launch_bounds__(256)
void gemm_nt(const float* __restrict__ A, const float* __restrict__ W,
             const float* __restrict__ bias, float* __restrict__ Cout)
{
    constexpr int K = ND;
    __shared__ float As[16][68];
    __shared__ float Bs[16][68];
    const int tid = threadIdx.x;
    const int tx = tid & 15, ty = tid >> 4;
    const int m0 = blockIdx.y * 64, n0 = blockIdx.x * 64;
    const int lrow = tid >> 2, lc4 = tid & 3;

    float c[4][4];
#pragma unroll
    for (int i = 0; i < 4; ++i)
#pragma unroll
        for (int j = 0; j < 4; ++j) c[i][j] = 0.f;

    const float* Aptr = A + (size_t)(m0 + lrow) * K + lc4 * 4;
    const float* Wptr = W + (size_t)(n0 + lrow) * K + lc4 * 4;

    for (int k0 = 0; k0 < K; k0 += 16) {
        float4 av = *(const float4*)(Aptr + k0);
        float4 bv = *(const float4*)(Wptr + k0);
        __syncthreads();
        As[lc4*4+0][lrow] = av.x; As[lc4*4+1][lrow] = av.y;
        As[lc4*4+2][lrow] = av.z; As[lc4*4+3][lrow] = av.w;
        Bs[lc4*4+0][lrow] = bv.x; Bs[lc4*4+1][lrow] = bv.y;
        Bs[lc4*4+2][lrow] = bv.z; Bs[lc4*4+3][lrow] = bv.w;
        __syncthreads();
#pragma unroll
        for (int k = 0; k < 16; ++k) {
            float4 a4 = *(const float4*)&As[k][ty*4];
            float4 b4 = *(const float4*)&Bs[k][tx*4];
            float aa[4] = {a4.x, a4.y, a4.z, a4.w};
            float bb[4] = {b4.x, b4.y, b4.z, b4.w};
#pragma unroll
            for (int i = 0; i < 4; ++i)
#pragma unroll
                for (int j = 0; j < 4; ++j)
                    c[i][j] = fmaf(aa[i], bb[j], c[i][j]);
        }
    }

    float4 bset = *(const float4*)&bias[n0 + tx*4];
    float bb[4] = {bset.x, bset.y, bset.z, bset.w};
#pragma unroll
    for (int i = 0; i < 4; ++i) {
        int m = m0 + ty*4 + i;
        float4 v;
        v.x = c[i][0] + bb[0]; v.y = c[i][1] + bb[1];
        v.z = c[i][2] + bb[2]; v.w = c[i][3] + bb[3];
        if (OUT_MODE == 0) {
            *(float4*)&Cout[(size_t)m * ND + n0 + tx*4] = v;
        } else {
            int b = m >> 10, s = m & (NS - 1);
            int h = n0 >> 6;
            *(float4*)&Cout[(((size_t)(b*NH + h))*NS + s)*NDH + tx*4] = v;
        }
    }
}

// ---------------------------------------------------------------------------
// Attention: one block = 64 q-rows of one (b,h). Per-batch uniform branch
// between dense (flash over 16 K-tiles of 64) and sparse (32 gathered keys).
// Thread map: wave w handles rows w*16..w*16+15; lane = (r in 16) + 16*cg;
// lane owns score cols cg*16+jj (dense) / cg*8+jj (sparse) and output
// dh = cg*16..cg*16+15. Row state (m,l) reduced across the 4 cg-lanes via
// shfl_xor 16/32.
// ---------------------------------------------------------------------------
__global__ __launch_bounds__(256)
void attn_kernel(const float* __restrict__ Q, const float* __restrict__ Km,
                 const float* __restrict__ Vm,
                 const int* __restrict__ pmask, const int* __restrict__ pidx,
                 const int* __restrict__ pimask,
                 const float* __restrict__ u_prev, float* __restrict__ OA)
{
    __shared__ float qs[64][68];
    __shared__ float Ks[64][68];
    __shared__ float Vs[64][68];
    __shared__ float Ps[64][68];

    const int tid  = threadIdx.x;
    const int lane = tid & 63, w = tid >> 6;
    const int r    = lane & 15;
    const int cg   = lane >> 4;
    const int row  = w * 16 + r;
    const int s0   = blockIdx.x * 64;
    const int h    = blockIdx.y, b = blockIdx.z;

    const float lam = 10.0f * __expf(-5.0f * u_prev[b]);
    const bool sparse = (lam >= 1.0f);

    const size_t headbase = ((size_t)(b*NH + h)) * NS * NDH;
    const float* Qh = Q  + headbase;
    const float* Kh = Km + headbase;
    const float* Vh = Vm + headbase;

    // stage q tile (64 x 64), coalesced
#pragma unroll
    for (int u = 0; u < 4; ++u) {
        int idx = u * 256 + tid;
        int rr = idx >> 4, c4 = idx & 15;
        *(float4*)&qs[rr][c4*4] = *(const float4*)&Qh[(size_t)(s0+rr)*NDH + c4*4];
    }
    __syncthreads();

    float4 qreg[16];
#pragma unroll
    for (int i4 = 0; i4 < 16; ++i4) qreg[i4] = *(const float4*)&qs[row][i4*4];

    float o[16];
#pragma unroll
    for (int i = 0; i < 16; ++i) o[i] = 0.f;
    float lsum = 0.f;

    if (!sparse) {
        float mrow = -INFINITY;
        for (int kt = 0; kt < 16; ++kt) {
            __syncthreads();
#pragma unroll
            for (int u = 0; u < 4; ++u) {
                int idx = u * 256 + tid;
                int rr = idx >> 4, c4 = idx & 15;
                *(float4*)&Ks[rr][c4*4] = *(const float4*)&Kh[(size_t)(kt*64+rr)*NDH + c4*4];
                *(float4*)&Vs[rr][c4*4] = *(const float4*)&Vh[(size_t)(kt*64+rr)*NDH + c4*4];
            }
            __syncthreads();

            float sc[16];
#pragma unroll
            for (int jj = 0; jj < 16; ++jj) {
                int j = cg*16 + jj;
                float4 a4 = {0.f, 0.f, 0.f, 0.f};
#pragma unroll
                for (int i4 = 0; i4 < 16; ++i4) {
                    float4 kv = *(const float4*)&Ks[j][i4*4];
                    a4.x = fmaf(qreg[i4].x, kv.x, a4.x);
                    a4.y = fmaf(qreg[i4].y, kv.y, a4.y);
                    a4.z = fmaf(qreg[i4].z, kv.z, a4.z);
                    a4.w = fmaf(qreg[i4].w, kv.w, a4.w);
                }
                float dot = (a4.x + a4.y) + (a4.z + a4.w);
                int kg = kt*64 + j;
                int mv = pmask[(size_t)(s0+row)*NS + kg];
                sc[jj] = dot * SCALE + (mv ? 0.f : -lam);
            }

            float mt = sc[0];
#pragma unroll
            for (int jj = 1; jj < 16; ++jj) mt = fmaxf(mt, sc[jj]);
            mt = fmaxf(mt, __shfl_xor(mt, 16));
            mt = fmaxf(mt, __shfl_xor(mt, 32));
            float mnew  = fmaxf(mrow, mt);
            float alpha = __expf(mrow - mnew);
            lsum *= alpha;
#pragma unroll
            for (int i = 0; i < 16; ++i) o[i] *= alpha;

            float psum = 0.f;
#pragma unroll
            for (int jj = 0; jj < 16; ++jj) {
                float p = __expf(sc[jj] - mnew);
                psum += p;
                Ps[row][cg*16 + jj] = p;
            }
            psum += __shfl_xor(psum, 16);
            psum += __shfl_xor(psum, 32);
            lsum += psum;
            mrow = mnew;
            __syncthreads();

#pragma unroll
            for (int j4 = 0; j4 < 16; ++j4) {
                float4 p4 = *(const float4*)&Ps[row][j4*4];
                float pv[4] = {p4.x, p4.y, p4.z, p4.w};
#pragma unroll
                for (int u2 = 0; u2 < 4; ++u2) {
                    int j = j4*4 + u2;
                    const float* vrow = &Vs[j][cg*16];
#pragma unroll
                    for (int i4 = 0; i4 < 4; ++i4) {
                        float4 vv = *(const float4*)&vrow[i4*4];
                        o[i4*4+0] = fmaf(pv[u2], vv.x, o[i4*4+0]);
                        o[i4*4+1] = fmaf(pv[u2], vv.y, o[i4*4+1]);
                        o[i4*4+2] = fmaf(pv[u2], vv.z, o[i4*4+2]);
                        o[i4*4+3] = fmaf(pv[u2], vv.w, o[i4*4+3]);
                    }
                }
            }
        }
    } else {
        // ---------------- sparse path ----------------
        float sc[8];
#pragma unroll
        for (int jj = 0; jj < 8; ++jj) {
            int j  = cg*8 + jj;
            int mv = pimask[(size_t)(s0+row)*NKSP + j];
            if (mv) {
                int kv = pidx[(size_t)(s0+row)*NKSP + j];
                const float* krow = &Kh[(size_t)kv * NDH];
                float4 a4 = {0.f, 0.f, 0.f, 0.f};
#pragma unroll
                for (int i4 = 0; i4 < 16; ++i4) {
                    float4 kk = *(const float4*)&krow[i4*4];
                    a4.x = fmaf(qreg[i4].x, kk.x, a4.x);
                    a4.y = fmaf(qreg[i4].y, kk.y, a4.y);
                    a4.z = fmaf(qreg[i4].z, kk.z, a4.z);
                    a4.w = fmaf(qreg[i4].w, kk.w, a4.w);
                }
                sc[jj] = ((a4.x + a4.y) + (a4.z + a4.w)) * SCALE;
            } else {
                sc[jj] = -INFINITY;
            }
        }
        float mt = sc[0];
#pragma unroll
        for (int jj = 1; jj < 8; ++jj) mt = fmaxf(mt, sc[jj]);
        mt = fmaxf(mt, __shfl_xor(mt, 16));
        mt = fmaxf(mt, __shfl_xor(mt, 32));

        float psum = 0.f;
#pragma unroll
        for (int jj = 0; jj < 8; ++jj) {
            float p = __expf(sc[jj] - mt);   // exp(-inf)=0 for masked
            psum += p;
            Ps[row][cg*8 + jj] = p;
        }
        psum += __shfl_xor(psum, 16);
        psum += __shfl_xor(psum, 32);
        lsum = psum;
        __syncthreads();

        for (int j = 0; j < 32; ++j) {
            float p = Ps[row][j];
            if (p != 0.f) {
                int kv = pidx[(size_t)(s0+row)*NKSP + j];
                const float* vrow = &Vh[(size_t)kv * NDH + cg*16];
#pragma unroll
                for (int i4 = 0; i4 < 4; ++i4) {
                    float4 vv = *(const float4*)&vrow[i4*4];
                    o[i4*4+0] = fmaf(p, vv.x, o[i4*4+0]);
                    o[i4*4+1] = fmaf(p, vv.y, o[i4*4+1]);
                    o[i4*4+2] = fmaf(p, vv.z, o[i4*4+2]);
                    o[i4*4+3] = fmaf(p, vv.w, o[i4*4+3]);
                }
            }
        }
    }

    float inv = 1.f / lsum;
    float* op = &OA[((size_t)b*NS + s0 + row)*ND + h*NDH + cg*16];
#pragma unroll
    for (int i4 = 0; i4 < 4; ++i4) {
        float4 v;
        v.x = o[i4*4+0]*inv; v.y = o[i4*4+1]*inv;
        v.z = o[i4*4+2]*inv; v.w = o[i4*4+3]*inv;
        *(float4*)&op[i4*4] = v;
    }
}

// ---------------------------------------------------------------------------
extern "C" void kernel_launch(void* const* d_in, const int* in_sizes, int n_in,
                              void* d_out, int out_size, void* d_ws, size_t ws_size,
                              hipStream_t stream)
{
    const float* x      = (const float*)d_in[0];
    const int*   pmask  = (const int*)  d_in[1];
    const int*   pidx   = (const int*)  d_in[2];
    const int*   pimask = (const int*)  d_in[3];
    const float* u_prev = (const float*)d_in[4];
    const float* Wq     = (const float*)d_in[5];
    const float* bq     = (const float*)d_in[6];
    const float* Wk     = (const float*)d_in[7];
    const float* bk     = (const float*)d_in[8];
    const float* Wv     = (const float*)d_in[9];
    const float* bv     = (const float*)d_in[10];
    const float* Wo     = (const float*)d_in[11];
    const float* bo     = (const float*)d_in[12];
    float* out = (float*)d_out;

    const size_t QSZ = (size_t)NB * NH * NS * NDH;   // 4,194,304 floats
    float* Qw = (float*)d_ws;
    float* Kw = Qw + QSZ;
    float* Vw = Kw + QSZ;
    float* Aw = Vw + QSZ;   // (B,S,D) attention output

    dim3 gg(ND/64, (NB*NS)/64);
    gemm_nt<1><<<gg, 256, 0, stream>>>(x, Wq, bq, Qw);
    gemm_nt<1><<<gg, 256, 0, stream>>>(x, Wk, bk, Kw);
    gemm_nt<1><<<gg, 256, 0, stream>>>(x, Wv, bv, Vw);

    attn_kernel<<<dim3(NS/64, NH, NB), 256, 0, stream>>>(
        Qw, Kw, Vw, pmask, pidx, pimask, u_prev, Aw);

    gemm_nt<0><<<gg, 256, 0, stream>>>(Aw, Wo, bo, out);
}

// Round 2
// 581.789 us; speedup vs baseline: 1.5950x; 1.5950x over previous
//
#include <hip/hip_runtime.h>
#include <hip/hip_bf16.h>
#include <cmath>

#define NB 4
#define NS 1024
#define ND 1024
#define NH 16
#define NDH 64
#define NKSP 32
#define SCALE 0.125f   // 1/sqrt(64)

typedef __attribute__((ext_vector_type(8))) short bf16x8;
typedef __attribute__((ext_vector_type(4))) float f32x4;

__device__ __forceinline__ ushort f2bf(float f) {
    union { __hip_bfloat16 h; ushort u; } cv;
    cv.h = __float2bfloat16(f);
    return cv.u;
}

// ---------------------------------------------------------------------------
// float -> bf16 elementwise convert (4 elems/thread)
// ---------------------------------------------------------------------------
__global__ __launch_bounds__(256)
void f2bf_kernel(const float* __restrict__ in, ushort* __restrict__ out, int n)
{
    int i = (blockIdx.x * 256 + threadIdx.x) * 4;
    if (i >= n) return;
    float4 v = *(const float4*)&in[i];
    ushort4 o;
    o.x = f2bf(v.x); o.y = f2bf(v.y); o.z = f2bf(v.z); o.w = f2bf(v.w);
    *(ushort4*)&out[i] = o;
}

// ---------------------------------------------------------------------------
// MFMA GEMM: C[M,N] = A[M,K](bf16) @ W[N,K](fp32, converted inline)^T + bias
// 128x128 tile, 256 threads (4 waves in 2x2), BK=32, mfma_f32_16x16x32_bf16.
// LDS tiles padded to 40 shorts/row (2-way bank aliasing only -> free).
// OUT_MODE 0: row-major (M,N) fp32. OUT_MODE 1: scatter to (B,H,S,DH) fp32.
// ---------------------------------------------------------------------------
template<int OUT_MODE>
__global__ __launch_bounds__(256)
void gemm_mfma(const ushort* __restrict__ A, const float* __restrict__ W,
               const float* __restrict__ bias, float* __restrict__ Cout)
{
    constexpr int K = ND;
    constexpr int LDT = 40;                 // padded LDS row stride (shorts)
    __shared__ short As[128 * LDT];
    __shared__ short Bs[128 * LDT];

    const int tid  = threadIdx.x;
    const int lane = tid & 63, w = tid >> 6;
    const int wm = w >> 1, wn = w & 1;
    const int m0 = blockIdx.y * 128, n0 = blockIdx.x * 128;
    const int quad = lane >> 4, l16 = lane & 15;

    f32x4 acc[4][4] = {};

    for (int k0 = 0; k0 < K; k0 += 32) {
        // global loads into regs first (latency overlaps previous compute)
        bf16x8 av[2];
        float4 wv[2][2];
#pragma unroll
        for (int u = 0; u < 2; ++u) {
            int t = u * 256 + tid;
            int row = t >> 2, kc = (t & 3) * 8;
            av[u] = *(const bf16x8*)(A + (size_t)(m0 + row) * K + k0 + kc);
            const float* wsrc = W + (size_t)(n0 + row) * K + k0 + kc;
            wv[u][0] = *(const float4*)wsrc;
            wv[u][1] = *(const float4*)(wsrc + 4);
        }
        __syncthreads();
#pragma unroll
        for (int u = 0; u < 2; ++u) {
            int t = u * 256 + tid;
            int row = t >> 2, kc = (t & 3) * 8;
            *(bf16x8*)&As[row * LDT + kc] = av[u];
            union { bf16x8 v; ushort s[8]; } bw;
            bw.s[0] = f2bf(wv[u][0].x); bw.s[1] = f2bf(wv[u][0].y);
            bw.s[2] = f2bf(wv[u][0].z); bw.s[3] = f2bf(wv[u][0].w);
            bw.s[4] = f2bf(wv[u][1].x); bw.s[5] = f2bf(wv[u][1].y);
            bw.s[6] = f2bf(wv[u][1].z); bw.s[7] = f2bf(wv[u][1].w);
            *(bf16x8*)&Bs[row * LDT + kc] = bw.v;
        }
        __syncthreads();

        bf16x8 af[4], bfr[4];
#pragma unroll
        for (int mt = 0; mt < 4; ++mt)
            af[mt] = *(const bf16x8*)&As[(wm*64 + mt*16 + l16) * LDT + quad*8];
#pragma unroll
        for (int nt = 0; nt < 4; ++nt)
            bfr[nt] = *(const bf16x8*)&Bs[(wn*64 + nt*16 + l16) * LDT + quad*8];
#pragma unroll
        for (int mt = 0; mt < 4; ++mt)
#pragma unroll
            for (int nt = 0; nt < 4; ++nt)
                acc[mt][nt] = __builtin_amdgcn_mfma_f32_16x16x32_bf16(
                    af[mt], bfr[nt], acc[mt][nt], 0, 0, 0);
    }

    // epilogue: C/D layout col=lane&15, row=quad*4+reg  (m89-verified)
#pragma unroll
    for (int nt = 0; nt < 4; ++nt) {
        int n = n0 + wn*64 + nt*16 + l16;
        float bz = bias[n];
#pragma unroll
        for (int mt = 0; mt < 4; ++mt) {
#pragma unroll
            for (int rg = 0; rg < 4; ++rg) {
                int m = m0 + wm*64 + mt*16 + quad*4 + rg;
                float val = acc[mt][nt][rg] + bz;
                if (OUT_MODE == 0) {
                    Cout[(size_t)m * ND + n] = val;
                } else {
                    int b = m >> 10, s = m & (NS - 1);
                    int hh = n >> 6, dh = n & 63;
                    Cout[(((size_t)(b*NH + hh))*NS + s)*NDH + dh] = val;
                }
            }
        }
    }
}

// ---------------------------------------------------------------------------
// Attention: one block = 64 q-rows of one (b,h). fp32 math, bf16 output.
// Dense: flash over 16 K-tiles of 64 (K/V staged in LDS, masks via int4
// global loads issued before the staging barrier). Sparse: 32 gathered keys.
// LDS = Ks+Vs+Ps = 52.2 KB -> 3 blocks/CU.
// ---------------------------------------------------------------------------
__global__ __launch_bounds__(256)
void attn_kernel(const float* __restrict__ Q, const float* __restrict__ Km,
                 const float* __restrict__ Vm,
                 const int* __restrict__ pmask, const int* __restrict__ pidx,
                 const int* __restrict__ pimask,
                 const float* __restrict__ u_prev, ushort* __restrict__ OA)
{
    __shared__ float Ks[64][68];
    __shared__ float Vs[64][68];
    __shared__ float Ps[64][68];

    const int tid  = threadIdx.x;
    const int lane = tid & 63, w = tid >> 6;
    const int r    = lane & 15;
    const int cg   = lane >> 4;
    const int row  = w * 16 + r;
    const int s0   = blockIdx.x * 64;
    const int h    = blockIdx.y, b = blockIdx.z;

    const float lam = 10.0f * __expf(-5.0f * u_prev[b]);
    const bool sparse = (lam >= 1.0f);

    const size_t headbase = ((size_t)(b*NH + h)) * NS * NDH;
    const float* Qh = Q  + headbase;
    const float* Kh = Km + headbase;
    const float* Vh = Vm + headbase;

    // q row straight to registers (4x redundant across cg lanes; cache-served)
    float4 qreg[16];
    const float* qp = Qh + (size_t)(s0 + row) * NDH;
#pragma unroll
    for (int i4 = 0; i4 < 16; ++i4) qreg[i4] = *(const float4*)(qp + i4*4);

    float o[16];
#pragma unroll
    for (int i = 0; i < 16; ++i) o[i] = 0.f;
    float lsum = 0.f;

    if (!sparse) {
        float mrow = -INFINITY;
        const int* mrow_ptr = pmask + (size_t)(s0 + row) * NS + cg * 16;
        for (int kt = 0; kt < 16; ++kt) {
            // mask loads first: latency overlaps the staging barrier
            int4 mv4[4];
#pragma unroll
            for (int j4 = 0; j4 < 4; ++j4)
                mv4[j4] = *(const int4*)(mrow_ptr + kt*64 + j4*4);

            __syncthreads();
#pragma unroll
            for (int u = 0; u < 4; ++u) {
                int idx = u * 256 + tid;
                int rr = idx >> 4, c4 = idx & 15;
                *(float4*)&Ks[rr][c4*4] = *(const float4*)&Kh[(size_t)(kt*64+rr)*NDH + c4*4];
                *(float4*)&Vs[rr][c4*4] = *(const float4*)&Vh[(size_t)(kt*64+rr)*NDH + c4*4];
            }
            __syncthreads();

            const int* mvp = (const int*)mv4;
            float sc[16];
#pragma unroll
            for (int jj = 0; jj < 16; ++jj) {
                int j = cg*16 + jj;
                float4 a4 = {0.f, 0.f, 0.f, 0.f};
#pragma unroll
                for (int i4 = 0; i4 < 16; ++i4) {
                    float4 kv = *(const float4*)&Ks[j][i4*4];
                    a4.x = fmaf(qreg[i4].x, kv.x, a4.x);
                    a4.y = fmaf(qreg[i4].y, kv.y, a4.y);
                    a4.z = fmaf(qreg[i4].z, kv.z, a4.z);
                    a4.w = fmaf(qreg[i4].w, kv.w, a4.w);
                }
                float dot = (a4.x + a4.y) + (a4.z + a4.w);
                sc[jj] = dot * SCALE + (mvp[jj] ? 0.f : -lam);
            }

            float mt = sc[0];
#pragma unroll
            for (int jj = 1; jj < 16; ++jj) mt = fmaxf(mt, sc[jj]);
            mt = fmaxf(mt, __shfl_xor(mt, 16));
            mt = fmaxf(mt, __shfl_xor(mt, 32));
            float mnew  = fmaxf(mrow, mt);
            float alpha = __expf(mrow - mnew);
            lsum *= alpha;
#pragma unroll
            for (int i = 0; i < 16; ++i) o[i] *= alpha;

            float psum = 0.f;
#pragma unroll
            for (int jj = 0; jj < 16; ++jj) {
                float p = __expf(sc[jj] - mnew);
                psum += p;
                Ps[row][cg*16 + jj] = p;
            }
            psum += __shfl_xor(psum, 16);
            psum += __shfl_xor(psum, 32);
            lsum += psum;
            mrow = mnew;
            // no barrier: Ps exchange is wave-internal (rows w*16..w*16+15),
            // same-wave DS ops complete in order.

#pragma unroll
            for (int j4 = 0; j4 < 16; ++j4) {
                float4 p4 = *(const float4*)&Ps[row][j4*4];
                float pv[4] = {p4.x, p4.y, p4.z, p4.w};
#pragma unroll
                for (int u2 = 0; u2 < 4; ++u2) {
                    int j = j4*4 + u2;
                    const float* vrow = &Vs[j][cg*16];
#pragma unroll
                    for (int i4 = 0; i4 < 4; ++i4) {
                        float4 vv = *(const float4*)&vrow[i4*4];
                        o[i4*4+0] = fmaf(pv[u2], vv.x, o[i4*4+0]);
                        o[i4*4+1] = fmaf(pv[u2], vv.y, o[i4*4+1]);
                        o[i4*4+2] = fmaf(pv[u2], vv.z, o[i4*4+2]);
                        o[i4*4+3] = fmaf(pv[u2], vv.w, o[i4*4+3]);
                    }
                }
            }
        }
    } else {
        // ---------------- sparse path ----------------
        float sc[8];
#pragma unroll
        for (int jj = 0; jj < 8; ++jj) {
            int j  = cg*8 + jj;
            int mv = pimask[(size_t)(s0+row)*NKSP + j];
            if (mv) {
                int kv = pidx[(size_t)(s0+row)*NKSP + j];
                const float* krow = &Kh[(size_t)kv * NDH];
                float4 a4 = {0.f, 0.f, 0.f, 0.f};
#pragma unroll
                for (int i4 = 0; i4 < 16; ++i4) {
                    float4 kk = *(const float4*)&krow[i4*4];
                    a4.x = fmaf(qreg[i4].x, kk.x, a4.x);
                    a4.y = fmaf(qreg[i4].y, kk.y, a4.y);
                    a4.z = fmaf(qreg[i4].z, kk.z, a4.z);
                    a4.w = fmaf(qreg[i4].w, kk.w, a4.w);
                }
                sc[jj] = ((a4.x + a4.y) + (a4.z + a4.w)) * SCALE;
            } else {
                sc[jj] = -INFINITY;
            }
        }
        float mt = sc[0];
#pragma unroll
        for (int jj = 1; jj < 8; ++jj) mt = fmaxf(mt, sc[jj]);
        mt = fmaxf(mt, __shfl_xor(mt, 16));
        mt = fmaxf(mt, __shfl_xor(mt, 32));

        float psum = 0.f;
#pragma unroll
        for (int jj = 0; jj < 8; ++jj) {
            float p = __expf(sc[jj] - mt);   // exp(-inf)=0 for masked
            psum += p;
            Ps[row][cg*8 + jj] = p;
        }
        psum += __shfl_xor(psum, 16);
        psum += __shfl_xor(psum, 32);
        lsum = psum;
        // no barrier: wave-internal Ps exchange

        for (int j = 0; j < 32; ++j) {
            float p = Ps[row][j];
            if (p != 0.f) {
                int kv = pidx[(size_t)(s0+row)*NKSP + j];
                const float* vrow = &Vh[(size_t)kv * NDH + cg*16];
#pragma unroll
                for (int i4 = 0; i4 < 4; ++i4) {
                    float4 vv = *(const float4*)&vrow[i4*4];
                    o[i4*4+0] = fmaf(p, vv.x, o[i4*4+0]);
                    o[i4*4+1] = fmaf(p, vv.y, o[i4*4+1]);
                    o[i4*4+2] = fmaf(p, vv.z, o[i4*4+2]);
                    o[i4*4+3] = fmaf(p, vv.w, o[i4*4+3]);
                }
            }
        }
    }

    float inv = 1.f / lsum;
    ushort* op = OA + ((size_t)b*NS + s0 + row)*ND + h*NDH + cg*16;
#pragma unroll
    for (int i4 = 0; i4 < 4; ++i4) {
        ushort4 v;
        v.x = f2bf(o[i4*4+0]*inv); v.y = f2bf(o[i4*4+1]*inv);
        v.z = f2bf(o[i4*4+2]*inv); v.w = f2bf(o[i4*4+3]*inv);
        *(ushort4*)(op + i4*4) = v;
    }
}

// ---------------------------------------------------------------------------
extern "C" void kernel_launch(void* const* d_in, const int* in_sizes, int n_in,
                              void* d_out, int out_size, void* d_ws, size_t ws_size,
                              hipStream_t stream)
{
    const float* x      = (const float*)d_in[0];
    const int*   pmask  = (const int*)  d_in[1];
    const int*   pidx   = (const int*)  d_in[2];
    const int*   pimask = (const int*)  d_in[3];
    const float* u_prev = (const float*)d_in[4];
    const float* Wq     = (const float*)d_in[5];
    const float* bq     = (const float*)d_in[6];
    const float* Wk     = (const float*)d_in[7];
    const float* bk     = (const float*)d_in[8];
    const float* Wv     = (const float*)d_in[9];
    const float* bv     = (const float*)d_in[10];
    const float* Wo     = (const float*)d_in[11];
    const float* bo     = (const float*)d_in[12];
    float* out = (float*)d_out;

    const size_t QSZ = (size_t)NB * NH * NS * NDH;   // 4,194,304
    ushort* xb  = (ushort*)d_ws;                     // bf16 x
    float*  Qw  = (float*)(xb + QSZ);
    float*  Kw  = Qw + QSZ;
    float*  Vw  = Kw + QSZ;
    ushort* Awb = (ushort*)(Vw + QSZ);               // bf16 attention output
    // total = 8.4 + 3*16.8 + 8.4 MB = 64 MiB (same footprint as round 1)

    f2bf_kernel<<<(NB*NS*ND)/(256*4), 256, 0, stream>>>(x, xb, NB*NS*ND);

    dim3 gg(ND/128, (NB*NS)/128);   // (8, 32)
    gemm_mfma<1><<<gg, 256, 0, stream>>>(xb, Wq, bq, Qw);
    gemm_mfma<1><<<gg, 256, 0, stream>>>(xb, Wk, bk, Kw);
    gemm_mfma<1><<<gg, 256, 0, stream>>>(xb, Wv, bv, Vw);

    attn_kernel<<<dim3(NS/64, NH, NB), 256, 0, stream>>>(
        Qw, Kw, Vw, pmask, pidx, pimask, u_prev, Awb);

    gemm_mfma<0><<<gg, 256, 0, stream>>>(Awb, Wo, bo, out);
}

// Round 3
// 329.093 us; speedup vs baseline: 2.8198x; 1.7679x over previous
//
#include <hip/hip_runtime.h>
#include <hip/hip_bf16.h>
#include <cmath>

#define NB 4
#define NS 1024
#define ND 1024
#define NH 16
#define NDH 64
#define NKSP 32
#define SCALE 0.125f   // 1/sqrt(64)

typedef __attribute__((ext_vector_type(8))) short bf16x8;
typedef __attribute__((ext_vector_type(4))) float f32x4;
typedef unsigned long long u64;

__device__ __forceinline__ ushort f2bf(float f) {
    union { __hip_bfloat16 h; ushort u; } cv;
    cv.h = __float2bfloat16(f);
    return cv.u;
}
__device__ __forceinline__ float bf2f(ushort u) {
    union { unsigned int i; float f; } cv;
    cv.i = ((unsigned int)u) << 16;
    return cv.f;
}

// ---------------------------------------------------------------------------
// float -> bf16 elementwise convert (4 elems/thread)
// ---------------------------------------------------------------------------
__global__ __launch_bounds__(256)
void f2bf_kernel(const float* __restrict__ in, ushort* __restrict__ out, int n)
{
    int i = (blockIdx.x * 256 + threadIdx.x) * 4;
    if (i >= n) return;
    float4 v = *(const float4*)&in[i];
    ushort4 o;
    o.x = f2bf(v.x); o.y = f2bf(v.y); o.z = f2bf(v.z); o.w = f2bf(v.w);
    *(ushort4*)&out[i] = o;
}

// ---------------------------------------------------------------------------
// pack pmask (S,S) int -> bitmask (S, S/64) u64. One wave per 64-bit word.
// ---------------------------------------------------------------------------
__global__ __launch_bounds__(256)
void pack_mask(const int* __restrict__ pm, u64* __restrict__ bm)
{
    int word = blockIdx.x * 4 + (threadIdx.x >> 6);
    int lane = threadIdx.x & 63;
    int row  = word >> 4, wcol = word & 15;
    int v = pm[(size_t)row * NS + wcol * 64 + lane];
    u64 b = __ballot(v != 0);
    if (lane == 0) bm[word] = b;
}

// ---------------------------------------------------------------------------
// V (b,h,s,dh) bf16 -> Vt (b,h,dh,s) bf16, 64x64 LDS tile transpose
// ---------------------------------------------------------------------------
__global__ __launch_bounds__(256)
void transpose_v(const ushort* __restrict__ Vb, ushort* __restrict__ Vt)
{
    __shared__ ushort L[64][68];
    int bh = blockIdx.y;
    int s0 = blockIdx.x * 64;
    int t  = threadIdx.x;
    int sl = t >> 2, c0 = (t & 3) * 16;
    const ushort* src = Vb + ((size_t)bh * NS + s0 + sl) * NDH + c0;
    *(bf16x8*)&L[sl][c0]     = *(const bf16x8*)src;
    *(bf16x8*)&L[sl][c0 + 8] = *(const bf16x8*)(src + 8);
    __syncthreads();
    int dh = t >> 2, sc = (t & 3) * 16;
    ushort tmp[16];
#pragma unroll
    for (int i = 0; i < 16; ++i) tmp[i] = L[sc + i][dh];
    ushort* dst = Vt + ((size_t)bh * NDH + dh) * NS + s0 + sc;
    *(bf16x8*)dst       = *(bf16x8*)&tmp[0];
    *(bf16x8*)(dst + 8) = *(bf16x8*)&tmp[8];
}

// ---------------------------------------------------------------------------
// MFMA GEMM: C[M,N] = A[M,K](bf16) @ W[N,K](fp32, converted inline)^T + bias
// 128x128 tile, 256 threads, BK=32, mfma_f32_16x16x32_bf16.
// OUT_MODE 0: row-major (M,N) fp32. OUT_MODE 1: scatter bf16 to (B,H,S,DH).
// ---------------------------------------------------------------------------
template<int OUT_MODE>
__global__ __launch_bounds__(256)
void gemm_mfma(const ushort* __restrict__ A, const float* __restrict__ W,
               const float* __restrict__ bias, void* __restrict__ CoutV)
{
    constexpr int K = ND;
    constexpr int LDT = 40;
    __shared__ short As[128 * LDT];
    __shared__ short Bs[128 * LDT];

    const int tid  = threadIdx.x;
    const int lane = tid & 63, w = tid >> 6;
    const int wm = w >> 1, wn = w & 1;
    const int m0 = blockIdx.y * 128, n0 = blockIdx.x * 128;
    const int quad = lane >> 4, l16 = lane & 15;

    f32x4 acc[4][4] = {};

    for (int k0 = 0; k0 < K; k0 += 32) {
        bf16x8 av[2];
        float4 wv[2][2];
#pragma unroll
        for (int u = 0; u < 2; ++u) {
            int t = u * 256 + tid;
            int row = t >> 2, kc = (t & 3) * 8;
            av[u] = *(const bf16x8*)(A + (size_t)(m0 + row) * K + k0 + kc);
            const float* wsrc = W + (size_t)(n0 + row) * K + k0 + kc;
            wv[u][0] = *(const float4*)wsrc;
            wv[u][1] = *(const float4*)(wsrc + 4);
        }
        __syncthreads();
#pragma unroll
        for (int u = 0; u < 2; ++u) {
            int t = u * 256 + tid;
            int row = t >> 2, kc = (t & 3) * 8;
            *(bf16x8*)&As[row * LDT + kc] = av[u];
            union { bf16x8 v; ushort s[8]; } bw;
            bw.s[0] = f2bf(wv[u][0].x); bw.s[1] = f2bf(wv[u][0].y);
            bw.s[2] = f2bf(wv[u][0].z); bw.s[3] = f2bf(wv[u][0].w);
            bw.s[4] = f2bf(wv[u][1].x); bw.s[5] = f2bf(wv[u][1].y);
            bw.s[6] = f2bf(wv[u][1].z); bw.s[7] = f2bf(wv[u][1].w);
            *(bf16x8*)&Bs[row * LDT + kc] = bw.v;
        }
        __syncthreads();

        bf16x8 af[4], bfr[4];
#pragma unroll
        for (int mt = 0; mt < 4; ++mt)
            af[mt] = *(const bf16x8*)&As[(wm*64 + mt*16 + l16) * LDT + quad*8];
#pragma unroll
        for (int nt = 0; nt < 4; ++nt)
            bfr[nt] = *(const bf16x8*)&Bs[(wn*64 + nt*16 + l16) * LDT + quad*8];
#pragma unroll
        for (int mt = 0; mt < 4; ++mt)
#pragma unroll
            for (int nt = 0; nt < 4; ++nt)
                acc[mt][nt] = __builtin_amdgcn_mfma_f32_16x16x32_bf16(
                    af[mt], bfr[nt], acc[mt][nt], 0, 0, 0);
    }

#pragma unroll
    for (int nt = 0; nt < 4; ++nt) {
        int n = n0 + wn*64 + nt*16 + l16;
        float bz = bias[n];
#pragma unroll
        for (int mt = 0; mt < 4; ++mt) {
#pragma unroll
            for (int rg = 0; rg < 4; ++rg) {
                int m = m0 + wm*64 + mt*16 + quad*4 + rg;
                float val = acc[mt][nt][rg] + bz;
                if (OUT_MODE == 0) {
                    ((float*)CoutV)[(size_t)m * ND + n] = val;
                } else {
                    int b = m >> 10, s = m & (NS - 1);
                    int hh = n >> 6, dh = n & 63;
                    ((ushort*)CoutV)[(((size_t)(b*NH + hh))*NS + s)*NDH + dh] = f2bf(val);
                }
            }
        }
    }
}

// ---------------------------------------------------------------------------
// MFMA flash attention. Block = 64 q-rows of one (b,h), 4 waves, wave w owns
// rows w*16..w*16+15. Dense: 16 K-tiles of 64; K + Vt staged in LDS; scores
// and PV via mfma_f32_16x16x32_bf16; mask from packed bitwords in LDS.
// Sparse: scalar fp32 path over 32 gathered keys (bf16 inputs).
// ---------------------------------------------------------------------------
__global__ __launch_bounds__(256)
void attn_kernel(const ushort* __restrict__ Qb, const ushort* __restrict__ Kb,
                 const ushort* __restrict__ Vb, const ushort* __restrict__ Vt,
                 const u64* __restrict__ bm,
                 const int* __restrict__ pidx, const int* __restrict__ pimask,
                 const float* __restrict__ u_prev, ushort* __restrict__ OA)
{
    __shared__ ushort Ks[64 * 72];
    __shared__ ushort Vts[64 * 72];
    __shared__ ushort Ps[64 * 68];
    __shared__ u64    MW[64 * 16];

    const int tid  = threadIdx.x;
    const int lane = tid & 63, w = tid >> 6;
    const int quad = lane >> 4, l16 = lane & 15;
    const int s0   = blockIdx.x * 64;
    const int h    = blockIdx.y, b = blockIdx.z;

    const float lam = 10.0f * __expf(-5.0f * u_prev[b]);
    const bool sparse = (lam >= 1.0f);

    const size_t bh = (size_t)b * NH + h;
    const ushort* Qh  = Qb + bh * NS * NDH;
    const ushort* Kh  = Kb + bh * NS * NDH;
    const ushort* Vh  = Vb + bh * NS * NDH;
    const ushort* Vth = Vt + bh * NDH * NS;

    if (!sparse) {
        // stage mask words for rows s0..s0+63 (1024 u64 = 8 KB)
#pragma unroll
        for (int u = 0; u < 4; ++u) {
            int idx = u * 256 + tid;
            MW[idx] = bm[(size_t)(s0 + (idx >> 4)) * 16 + (idx & 15)];
        }

        // Q A-fragments (rows w*16+l16)
        bf16x8 qf[2];
#pragma unroll
        for (int kk = 0; kk < 2; ++kk)
            qf[kk] = *(const bf16x8*)&Qh[(size_t)(s0 + w*16 + l16) * NDH + kk*32 + quad*8];

        f32x4 o_acc[4] = {};
        float mrow[4], lsum[4];
#pragma unroll
        for (int rg = 0; rg < 4; ++rg) { mrow[rg] = -INFINITY; lsum[rg] = 0.f; }

        const int sl = tid >> 2, c0 = (tid & 3) * 16;

        for (int kt = 0; kt < 16; ++kt) {
            __syncthreads();
            // stage K tile (key-major) and Vt tile (dh-major)
            {
                const ushort* ksrc = &Kh[(size_t)(kt*64 + sl) * NDH + c0];
                *(bf16x8*)&Ks[sl*72 + c0]     = *(const bf16x8*)ksrc;
                *(bf16x8*)&Ks[sl*72 + c0 + 8] = *(const bf16x8*)(ksrc + 8);
                const ushort* vsrc = &Vth[(size_t)sl * NS + kt*64 + c0];
                *(bf16x8*)&Vts[sl*72 + c0]     = *(const bf16x8*)vsrc;
                *(bf16x8*)&Vts[sl*72 + c0 + 8] = *(const bf16x8*)(vsrc + 8);
            }
            __syncthreads();

            // scores: Q(16x64) @ K^T(64x64) -> C layout
            f32x4 s_acc[4] = {};
#pragma unroll
            for (int nt = 0; nt < 4; ++nt)
#pragma unroll
                for (int kk = 0; kk < 2; ++kk) {
                    bf16x8 kf = *(const bf16x8*)&Ks[(nt*16 + l16)*72 + kk*32 + quad*8];
                    s_acc[nt] = __builtin_amdgcn_mfma_f32_16x16x32_bf16(
                        qf[kk], kf, s_acc[nt], 0, 0, 0);
                }

            // mask + scale
            u64 wv[4];
#pragma unroll
            for (int rg = 0; rg < 4; ++rg)
                wv[rg] = MW[(w*16 + quad*4 + rg) * 16 + kt];
#pragma unroll
            for (int nt = 0; nt < 4; ++nt)
#pragma unroll
                for (int rg = 0; rg < 4; ++rg) {
                    float bias = ((wv[rg] >> (nt*16 + l16)) & 1ULL) ? 0.f : -lam;
                    s_acc[nt][rg] = s_acc[nt][rg] * SCALE + bias;
                }

            // online softmax (row = quad*4+rg; reduce across l16 lanes)
            float mx[4];
#pragma unroll
            for (int rg = 0; rg < 4; ++rg) {
                float m = s_acc[0][rg];
#pragma unroll
                for (int nt = 1; nt < 4; ++nt) m = fmaxf(m, s_acc[nt][rg]);
                m = fmaxf(m, __shfl_xor(m, 1));
                m = fmaxf(m, __shfl_xor(m, 2));
                m = fmaxf(m, __shfl_xor(m, 4));
                m = fmaxf(m, __shfl_xor(m, 8));
                mx[rg] = m;
            }
            float alpha[4], psum[4];
#pragma unroll
            for (int rg = 0; rg < 4; ++rg) {
                float mnew = fmaxf(mrow[rg], mx[rg]);
                alpha[rg] = __expf(mrow[rg] - mnew);
                mrow[rg] = mnew;
                psum[rg] = 0.f;
            }
#pragma unroll
            for (int nt = 0; nt < 4; ++nt)
#pragma unroll
                for (int rg = 0; rg < 4; ++rg) {
                    float p = __expf(s_acc[nt][rg] - mrow[rg]);
                    psum[rg] += p;
                    Ps[(w*16 + quad*4 + rg) * 68 + nt*16 + l16] = f2bf(p);
                }
#pragma unroll
            for (int rg = 0; rg < 4; ++rg) {
                float ps = psum[rg];
                ps += __shfl_xor(ps, 1);
                ps += __shfl_xor(ps, 2);
                ps += __shfl_xor(ps, 4);
                ps += __shfl_xor(ps, 8);
                lsum[rg] = lsum[rg] * alpha[rg] + ps;
            }
#pragma unroll
            for (int nt = 0; nt < 4; ++nt)
#pragma unroll
                for (int rg = 0; rg < 4; ++rg)
                    o_acc[nt][rg] *= alpha[rg];

            // PV: P(16x64) @ Vt^T -> accumulate (wave-internal P exchange)
            bf16x8 pf[2];
#pragma unroll
            for (int kk = 0; kk < 2; ++kk)
                pf[kk] = *(const bf16x8*)&Ps[(w*16 + l16)*68 + kk*32 + quad*8];
#pragma unroll
            for (int nt = 0; nt < 4; ++nt)
#pragma unroll
                for (int kk = 0; kk < 2; ++kk) {
                    bf16x8 vf = *(const bf16x8*)&Vts[(nt*16 + l16)*72 + kk*32 + quad*8];
                    o_acc[nt] = __builtin_amdgcn_mfma_f32_16x16x32_bf16(
                        pf[kk], vf, o_acc[nt], 0, 0, 0);
                }
        }

        // epilogue
        float inv[4];
#pragma unroll
        for (int rg = 0; rg < 4; ++rg) inv[rg] = 1.f / lsum[rg];
#pragma unroll
        for (int nt = 0; nt < 4; ++nt)
#pragma unroll
            for (int rg = 0; rg < 4; ++rg) {
                int m = w*16 + quad*4 + rg;
                OA[((size_t)b*NS + s0 + m)*ND + h*NDH + nt*16 + l16] =
                    f2bf(o_acc[nt][rg] * inv[rg]);
            }
    } else {
        // ---------------- sparse path (fp32 scalar, bf16 inputs) ----------
        const int r   = lane & 15;
        const int cg  = lane >> 4;
        const int row = w * 16 + r;

        float qreg[64];
        {
            const ushort* qp = Qh + (size_t)(s0 + row) * NDH;
#pragma unroll
            for (int c = 0; c < 8; ++c) {
                union { bf16x8 v; ushort s[8]; } qv;
                qv.v = *(const bf16x8*)(qp + c*8);
#pragma unroll
                for (int j = 0; j < 8; ++j) qreg[c*8 + j] = bf2f(qv.s[j]);
            }
        }

        float sc[8];
#pragma unroll
        for (int jj = 0; jj < 8; ++jj) {
            int j  = cg*8 + jj;
            int mv = pimask[(size_t)(s0+row)*NKSP + j];
            if (mv) {
                int kv = pidx[(size_t)(s0+row)*NKSP + j];
                const ushort* krow = &Kh[(size_t)kv * NDH];
                float acc = 0.f;
#pragma unroll
                for (int c = 0; c < 8; ++c) {
                    union { bf16x8 v; ushort s[8]; } kk;
                    kk.v = *(const bf16x8*)(krow + c*8);
#pragma unroll
                    for (int jb = 0; jb < 8; ++jb)
                        acc = fmaf(qreg[c*8 + jb], bf2f(kk.s[jb]), acc);
                }
                sc[jj] = acc * SCALE;
            } else {
                sc[jj] = -INFINITY;
            }
        }
        float mt = sc[0];
#pragma unroll
        for (int jj = 1; jj < 8; ++jj) mt = fmaxf(mt, sc[jj]);
        mt = fmaxf(mt, __shfl_xor(mt, 16));
        mt = fmaxf(mt, __shfl_xor(mt, 32));

        float psum = 0.f;
#pragma unroll
        for (int jj = 0; jj < 8; ++jj) {
            float p = __expf(sc[jj] - mt);
            psum += p;
            Ps[row * 68 + cg*8 + jj] = f2bf(p);
        }
        psum += __shfl_xor(psum, 16);
        psum += __shfl_xor(psum, 32);

        float o[16];
#pragma unroll
        for (int i = 0; i < 16; ++i) o[i] = 0.f;

        for (int j = 0; j < 32; ++j) {
            float p = bf2f(Ps[row * 68 + j]);
            if (p != 0.f) {
                int kv = pidx[(size_t)(s0+row)*NKSP + j];
                const ushort* vrow = &Vh[(size_t)kv * NDH + cg*16];
#pragma unroll
                for (int c = 0; c < 2; ++c) {
                    union { bf16x8 v; ushort s[8]; } vv;
                    vv.v = *(const bf16x8*)(vrow + c*8);
#pragma unroll
                    for (int jb = 0; jb < 8; ++jb)
                        o[c*8 + jb] = fmaf(p, bf2f(vv.s[jb]), o[c*8 + jb]);
                }
            }
        }

        float inv = 1.f / psum;
        ushort* op = OA + ((size_t)b*NS + s0 + row)*ND + h*NDH + cg*16;
#pragma unroll
        for (int i4 = 0; i4 < 4; ++i4) {
            ushort4 v;
            v.x = f2bf(o[i4*4+0]*inv); v.y = f2bf(o[i4*4+1]*inv);
            v.z = f2bf(o[i4*4+2]*inv); v.w = f2bf(o[i4*4+3]*inv);
            *(ushort4*)(op + i4*4) = v;
        }
    }
}

// ---------------------------------------------------------------------------
extern "C" void kernel_launch(void* const* d_in, const int* in_sizes, int n_in,
                              void* d_out, int out_size, void* d_ws, size_t ws_size,
                              hipStream_t stream)
{
    const float* x      = (const float*)d_in[0];
    const int*   pmask  = (const int*)  d_in[1];
    const int*   pidx   = (const int*)  d_in[2];
    const int*   pimask = (const int*)  d_in[3];
    const float* u_prev = (const float*)d_in[4];
    const float* Wq     = (const float*)d_in[5];
    const float* bq     = (const float*)d_in[6];
    const float* Wk     = (const float*)d_in[7];
    const float* bk     = (const float*)d_in[8];
    const float* Wv     = (const float*)d_in[9];
    const float* bv     = (const float*)d_in[10];
    const float* Wo     = (const float*)d_in[11];
    const float* bo     = (const float*)d_in[12];
    float* out = (float*)d_out;

    const size_t QSZ = (size_t)NB * NH * NS * NDH;   // 4,194,304 elements
    ushort* xb  = (ushort*)d_ws;        // bf16 x            (8 MB)
    ushort* Qw  = xb  + QSZ;            // bf16 Q (b,h,s,dh) (8 MB)
    ushort* Kw  = Qw  + QSZ;            // bf16 K            (8 MB)
    ushort* Vw  = Kw  + QSZ;            // bf16 V            (8 MB)
    ushort* Vtw = Vw  + QSZ;            // bf16 V^T (b,h,dh,s) (8 MB)
    ushort* Awb = Vtw + QSZ;            // bf16 attn out (b,s,d) (8 MB)
    u64*    bmw = (u64*)(Awb + QSZ);    // packed mask (128 KB)

    f2bf_kernel<<<(NB*NS*ND)/(256*4), 256, 0, stream>>>(x, xb, NB*NS*ND);
    pack_mask<<<(NS*NS/64)/4, 256, 0, stream>>>(pmask, bmw);

    dim3 gg(ND/128, (NB*NS)/128);   // (8, 32)
    gemm_mfma<1><<<gg, 256, 0, stream>>>(xb, Wq, bq, Qw);
    gemm_mfma<1><<<gg, 256, 0, stream>>>(xb, Wk, bk, Kw);
    gemm_mfma<1><<<gg, 256, 0, stream>>>(xb, Wv, bv, Vw);

    transpose_v<<<dim3(NS/64, NB*NH), 256, 0, stream>>>(Vw, Vtw);

    attn_kernel<<<dim3(NS/64, NH, NB), 256, 0, stream>>>(
        Qw, Kw, Vw, Vtw, bmw, pidx, pimask, u_prev, Awb);

    gemm_mfma<0><<<gg, 256, 0, stream>>>(Awb, Wo, bo, out);
}

// Round 4
// 251.506 us; speedup vs baseline: 3.6897x; 1.3085x over previous
//
#include <hip/hip_runtime.h>
#include <hip/hip_bf16.h>
#include <cmath>

#define NB 4
#define NS 1024
#define ND 1024
#define NH 16
#define NDH 64
#define NKSP 32
#define SCALE 0.125f   // 1/sqrt(64)

typedef __attribute__((ext_vector_type(8))) short bf16x8;
typedef __attribute__((ext_vector_type(4))) float f32x4;
typedef unsigned long long u64;

#define AS1 __attribute__((address_space(1)))
#define AS3 __attribute__((address_space(3)))

__device__ __forceinline__ void gl_lds16(const void* g, void* l) {
    // async global->LDS, 16B/lane; LDS dest = wave-uniform base + lane*16
    __builtin_amdgcn_global_load_lds((const AS1 void*)g, (AS3 void*)l, 16, 0, 0);
}

__device__ __forceinline__ ushort f2bf(float f) {
    union { __hip_bfloat16 h; ushort u; } cv;
    cv.h = __float2bfloat16(f);
    return cv.u;
}
__device__ __forceinline__ float bf2f(ushort u) {
    union { unsigned int i; float f; } cv;
    cv.i = ((unsigned int)u) << 16;
    return cv.f;
}

// ---------------------------------------------------------------------------
// fp32 -> bf16 for x (y=0, 4096 blocks) and Wq/Wk/Wv/Wo (y=1..4, 1024 blocks)
// ---------------------------------------------------------------------------
__global__ __launch_bounds__(256)
void f2bf_multi(const float* __restrict__ x,
                const float* __restrict__ w0, const float* __restrict__ w1,
                const float* __restrict__ w2, const float* __restrict__ w3,
                ushort* __restrict__ xo,
                ushort* __restrict__ o0, ushort* __restrict__ o1,
                ushort* __restrict__ o2, ushort* __restrict__ o3)
{
    int y = blockIdx.y;
    const float* src; ushort* dst; int nblk;
    if (y == 0)      { src = x;  dst = xo; nblk = 4096; }
    else if (y == 1) { src = w0; dst = o0; nblk = 1024; }
    else if (y == 2) { src = w1; dst = o1; nblk = 1024; }
    else if (y == 3) { src = w2; dst = o2; nblk = 1024; }
    else             { src = w3; dst = o3; nblk = 1024; }
    if (blockIdx.x >= (unsigned)nblk) return;
    int i = (blockIdx.x * 256 + threadIdx.x) * 4;
    float4 v = *(const float4*)&src[i];
    ushort4 o;
    o.x = f2bf(v.x); o.y = f2bf(v.y); o.z = f2bf(v.z); o.w = f2bf(v.w);
    *(ushort4*)&dst[i] = o;
}

// ---------------------------------------------------------------------------
// pack pmask (S,S) int -> bitmask (S, S/64) u64. One wave per 64-bit word.
// ---------------------------------------------------------------------------
__global__ __launch_bounds__(256)
void pack_mask(const int* __restrict__ pm, u64* __restrict__ bm)
{
    int word = blockIdx.x * 4 + (threadIdx.x >> 6);
    int lane = threadIdx.x & 63;
    int row  = word >> 4, wcol = word & 15;
    int v = pm[(size_t)row * NS + wcol * 64 + lane];
    u64 b = __ballot(v != 0);
    if (lane == 0) bm[word] = b;
}

// ---------------------------------------------------------------------------
// V (b,h,s,dh) bf16 -> Vt (b,h,dh,s) bf16, 64x64 LDS tile transpose
// ---------------------------------------------------------------------------
__global__ __launch_bounds__(256)
void transpose_v(const ushort* __restrict__ Vb, ushort* __restrict__ Vt)
{
    __shared__ __attribute__((aligned(16))) ushort L[64][68];
    int bh = blockIdx.y;
    int s0 = blockIdx.x * 64;
    int t  = threadIdx.x;
    int sl = t >> 2, c0 = (t & 3) * 16;
    const ushort* src = Vb + ((size_t)bh * NS + s0 + sl) * NDH + c0;
    *(bf16x8*)&L[sl][c0]     = *(const bf16x8*)src;
    *(bf16x8*)&L[sl][c0 + 8] = *(const bf16x8*)(src + 8);
    __syncthreads();
    int dh = t >> 2, sc = (t & 3) * 16;
    ushort tmp[16];
#pragma unroll
    for (int i = 0; i < 16; ++i) tmp[i] = L[sc + i][dh];
    ushort* dst = Vt + ((size_t)bh * NDH + dh) * NS + s0 + sc;
    *(bf16x8*)dst       = *(bf16x8*)&tmp[0];
    *(bf16x8*)(dst + 8) = *(bf16x8*)&tmp[8];
}

// ---------------------------------------------------------------------------
// Fused QKV GEMM: out = x(bf16,4096x1024) @ W{q,k,v}(bf16,1024x1024)^T + b
// 128x128 tile, BK=32, global_load_lds width-16 staging (m97 structure),
// scatter bf16 to (B,H,S,DH). grid (24,32): blockIdx.x: [0,8)=Q [8,16)=K
// [16,24)=V.
// ---------------------------------------------------------------------------
__global__ __launch_bounds__(256)
void gemm_qkv(const ushort* __restrict__ xb,
              const ushort* __restrict__ Wqb, const ushort* __restrict__ Wkb,
              const ushort* __restrict__ Wvb,
              const float* __restrict__ bq, const float* __restrict__ bk,
              const float* __restrict__ bv,
              ushort* __restrict__ Qo, ushort* __restrict__ Ko,
              ushort* __restrict__ Vo)
{
    constexpr int K = ND;
    __shared__ __attribute__((aligned(16))) ushort As[128 * 32];
    __shared__ __attribute__((aligned(16))) ushort Bs[128 * 32];

    const int tid  = threadIdx.x;
    const int lane = tid & 63, w = tid >> 6;
    const int wm = w >> 1, wn = w & 1;
    const int which = blockIdx.x >> 3;
    const int n0 = (blockIdx.x & 7) * 128;
    const int m0 = blockIdx.y * 128;
    const int quad = lane >> 4, l16 = lane & 15;

    const ushort* W = (which == 0) ? Wqb : (which == 1) ? Wkb : Wvb;
    const float* bias = (which == 0) ? bq : (which == 1) ? bk : bv;
    ushort* Out = (which == 0) ? Qo : (which == 1) ? Ko : Vo;

    f32x4 acc[4][4] = {};

    for (int k0 = 0; k0 < K; k0 += 32) {
        __syncthreads();
#pragma unroll
        for (int u = 0; u < 2; ++u) {
            int t0 = u * 256 + w * 64;          // wave-uniform chunk base
            int t  = t0 + lane;
            int row = t >> 2, kc = (t & 3) * 8;
            gl_lds16(xb + (size_t)(m0 + row) * K + k0 + kc, &As[t0 * 8]);
            gl_lds16(W  + (size_t)(n0 + row) * K + k0 + kc, &Bs[t0 * 8]);
        }
        __syncthreads();

        bf16x8 af[4], bfr[4];
#pragma unroll
        for (int mt = 0; mt < 4; ++mt)
            af[mt] = *(const bf16x8*)&As[(wm*64 + mt*16 + l16) * 32 + quad*8];
#pragma unroll
        for (int nt = 0; nt < 4; ++nt)
            bfr[nt] = *(const bf16x8*)&Bs[(wn*64 + nt*16 + l16) * 32 + quad*8];
#pragma unroll
        for (int mt = 0; mt < 4; ++mt)
#pragma unroll
            for (int nt = 0; nt < 4; ++nt)
                acc[mt][nt] = __builtin_amdgcn_mfma_f32_16x16x32_bf16(
                    af[mt], bfr[nt], acc[mt][nt], 0, 0, 0);
    }

#pragma unroll
    for (int nt = 0; nt < 4; ++nt) {
        int n = n0 + wn*64 + nt*16 + l16;
        float bz = bias[n];
        int hh = n >> 6, dh = n & 63;
#pragma unroll
        for (int mt = 0; mt < 4; ++mt) {
#pragma unroll
            for (int rg = 0; rg < 4; ++rg) {
                int m = m0 + wm*64 + mt*16 + quad*4 + rg;
                int b = m >> 10, s = m & (NS - 1);
                Out[(((size_t)(b*NH + hh))*NS + s)*NDH + dh] =
                    f2bf(acc[mt][nt][rg] + bz);
            }
        }
    }
}

// ---------------------------------------------------------------------------
// Output GEMM: out = Aw(bf16,4096x1024) @ Wo(bf16)^T + bo, fp32 out.
// 64x128 tile -> 512 blocks (2/CU). Waves: wm=w&1 (32-row half),
// wn=w>>1 (64-col half); acc[2][4].
// ---------------------------------------------------------------------------
__global__ __launch_bounds__(256)
void gemm_out(const ushort* __restrict__ A, const ushort* __restrict__ W,
              const float* __restrict__ bias, float* __restrict__ Cout)
{
    constexpr int K = ND;
    __shared__ __attribute__((aligned(16))) ushort As[64 * 32];
    __shared__ __attribute__((aligned(16))) ushort Bs[128 * 32];

    const int tid  = threadIdx.x;
    const int lane = tid & 63, w = tid >> 6;
    const int wm = w & 1, wn = w >> 1;
    const int m0 = blockIdx.y * 64, n0 = blockIdx.x * 128;
    const int quad = lane >> 4, l16 = lane & 15;

    f32x4 acc[2][4] = {};

    for (int k0 = 0; k0 < K; k0 += 32) {
        __syncthreads();
        {
            int t0 = w * 64;
            int t  = t0 + lane;
            int row = t >> 2, kc = (t & 3) * 8;
            gl_lds16(A + (size_t)(m0 + row) * K + k0 + kc, &As[t0 * 8]);
        }
#pragma unroll
        for (int u = 0; u < 2; ++u) {
            int t0 = u * 256 + w * 64;
            int t  = t0 + lane;
            int row = t >> 2, kc = (t & 3) * 8;
            gl_lds16(W + (size_t)(n0 + row) * K + k0 + kc, &Bs[t0 * 8]);
        }
        __syncthreads();

        bf16x8 af[2], bfr[4];
#pragma unroll
        for (int mt = 0; mt < 2; ++mt)
            af[mt] = *(const bf16x8*)&As[(wm*32 + mt*16 + l16) * 32 + quad*8];
#pragma unroll
        for (int nt = 0; nt < 4; ++nt)
            bfr[nt] = *(const bf16x8*)&Bs[(wn*64 + nt*16 + l16) * 32 + quad*8];
#pragma unroll
        for (int mt = 0; mt < 2; ++mt)
#pragma unroll
            for (int nt = 0; nt < 4; ++nt)
                acc[mt][nt] = __builtin_amdgcn_mfma_f32_16x16x32_bf16(
                    af[mt], bfr[nt], acc[mt][nt], 0, 0, 0);
    }

#pragma unroll
    for (int nt = 0; nt < 4; ++nt) {
        int n = n0 + wn*64 + nt*16 + l16;
        float bz = bias[n];
#pragma unroll
        for (int mt = 0; mt < 2; ++mt) {
#pragma unroll
            for (int rg = 0; rg < 4; ++rg) {
                int m = m0 + wm*32 + mt*16 + quad*4 + rg;
                Cout[(size_t)m * ND + n] = acc[mt][nt][rg] + bz;
            }
        }
    }
}

// ---------------------------------------------------------------------------
// MFMA flash attention, 128 q-rows per block. Wave w owns rows w*32..w*32+31
// (two 16-row groups qh). Dense: 16 K-tiles of 64 keys; K+Vt staged in LDS;
// QK^T and PV via mfma_f32_16x16x32_bf16; mask via packed bitwords in LDS.
// Sparse: scalar fp32 over 32 gathered keys. LDS 52.2 KB -> 3 blocks/CU.
// ---------------------------------------------------------------------------
__global__ __launch_bounds__(256)
void attn_kernel(const ushort* __restrict__ Qb, const ushort* __restrict__ Kb,
                 const ushort* __restrict__ Vb, const ushort* __restrict__ Vt,
                 const u64* __restrict__ bm,
                 const int* __restrict__ pidx, const int* __restrict__ pimask,
                 const float* __restrict__ u_prev, ushort* __restrict__ OA)
{
    __shared__ __attribute__((aligned(16))) ushort Ks[64 * 72];
    __shared__ __attribute__((aligned(16))) ushort Vts[64 * 72];
    __shared__ __attribute__((aligned(16))) ushort Ps[128 * 68];
    __shared__ __attribute__((aligned(16))) u64    MW[128 * 16];

    const int tid  = threadIdx.x;
    const int lane = tid & 63, w = tid >> 6;
    const int quad = lane >> 4, l16 = lane & 15;
    const int s0   = blockIdx.x * 128;
    const int h    = blockIdx.y, b = blockIdx.z;

    const float lam = 10.0f * __expf(-5.0f * u_prev[b]);
    const bool sparse = (lam >= 1.0f);

    const size_t bh = (size_t)b * NH + h;
    const ushort* Qh  = Qb + bh * NS * NDH;
    const ushort* Kh  = Kb + bh * NS * NDH;
    const ushort* Vh  = Vb + bh * NS * NDH;
    const ushort* Vth = Vt + bh * NDH * NS;

    if (!sparse) {
        // stage mask words for rows s0..s0+127 (2048 u64 = 16 KB)
#pragma unroll
        for (int u = 0; u < 8; ++u) {
            int idx = u * 256 + tid;
            MW[idx] = bm[(size_t)(s0 + (idx >> 4)) * 16 + (idx & 15)];
        }

        // Q A-fragments for both 16-row groups
        bf16x8 qf[2][2];
#pragma unroll
        for (int qh = 0; qh < 2; ++qh)
#pragma unroll
            for (int kk = 0; kk < 2; ++kk)
                qf[qh][kk] = *(const bf16x8*)
                    &Qh[(size_t)(s0 + w*32 + qh*16 + l16) * NDH + kk*32 + quad*8];

        f32x4 o_acc[2][4] = {};
        float mrow[2][4], lsum[2][4];
#pragma unroll
        for (int qh = 0; qh < 2; ++qh)
#pragma unroll
            for (int rg = 0; rg < 4; ++rg) { mrow[qh][rg] = -INFINITY; lsum[qh][rg] = 0.f; }

        const int sl = tid >> 2, c0 = (tid & 3) * 16;

        for (int kt = 0; kt < 16; ++kt) {
            __syncthreads();
            {
                const ushort* ksrc = &Kh[(size_t)(kt*64 + sl) * NDH + c0];
                *(bf16x8*)&Ks[sl*72 + c0]     = *(const bf16x8*)ksrc;
                *(bf16x8*)&Ks[sl*72 + c0 + 8] = *(const bf16x8*)(ksrc + 8);
                const ushort* vsrc = &Vth[(size_t)sl * NS + kt*64 + c0];
                *(bf16x8*)&Vts[sl*72 + c0]     = *(const bf16x8*)vsrc;
                *(bf16x8*)&Vts[sl*72 + c0 + 8] = *(const bf16x8*)(vsrc + 8);
            }
            __syncthreads();

#pragma unroll
            for (int qh = 0; qh < 2; ++qh) {
                // scores: Q(16x64) @ K^T -> C layout
                f32x4 s_acc[4] = {};
#pragma unroll
                for (int nt = 0; nt < 4; ++nt)
#pragma unroll
                    for (int kk = 0; kk < 2; ++kk) {
                        bf16x8 kf = *(const bf16x8*)&Ks[(nt*16 + l16)*72 + kk*32 + quad*8];
                        s_acc[nt] = __builtin_amdgcn_mfma_f32_16x16x32_bf16(
                            qf[qh][kk], kf, s_acc[nt], 0, 0, 0);
                    }

                // mask + scale
                u64 wv[4];
#pragma unroll
                for (int rg = 0; rg < 4; ++rg)
                    wv[rg] = MW[(w*32 + qh*16 + quad*4 + rg) * 16 + kt];
#pragma unroll
                for (int nt = 0; nt < 4; ++nt)
#pragma unroll
                    for (int rg = 0; rg < 4; ++rg) {
                        float bias = ((wv[rg] >> (nt*16 + l16)) & 1ULL) ? 0.f : -lam;
                        s_acc[nt][rg] = s_acc[nt][rg] * SCALE + bias;
                    }

                // online softmax (row = quad*4+rg; reduce across l16 lanes)
                float mx[4];
#pragma unroll
                for (int rg = 0; rg < 4; ++rg) {
                    float m = s_acc[0][rg];
#pragma unroll
                    for (int nt = 1; nt < 4; ++nt) m = fmaxf(m, s_acc[nt][rg]);
                    m = fmaxf(m, __shfl_xor(m, 1));
                    m = fmaxf(m, __shfl_xor(m, 2));
                    m = fmaxf(m, __shfl_xor(m, 4));
                    m = fmaxf(m, __shfl_xor(m, 8));
                    mx[rg] = m;
                }
                float alpha[4], psum[4];
#pragma unroll
                for (int rg = 0; rg < 4; ++rg) {
                    float mnew = fmaxf(mrow[qh][rg], mx[rg]);
                    alpha[rg] = __expf(mrow[qh][rg] - mnew);
                    mrow[qh][rg] = mnew;
                    psum[rg] = 0.f;
                }
#pragma unroll
                for (int nt = 0; nt < 4; ++nt)
#pragma unroll
                    for (int rg = 0; rg < 4; ++rg) {
                        float p = __expf(s_acc[nt][rg] - mrow[qh][rg]);
                        psum[rg] += p;
                        Ps[(w*32 + qh*16 + quad*4 + rg) * 68 + nt*16 + l16] = f2bf(p);
                    }
#pragma unroll
                for (int rg = 0; rg < 4; ++rg) {
                    float ps = psum[rg];
                    ps += __shfl_xor(ps, 1);
                    ps += __shfl_xor(ps, 2);
                    ps += __shfl_xor(ps, 4);
                    ps += __shfl_xor(ps, 8);
                    lsum[qh][rg] = lsum[qh][rg] * alpha[rg] + ps;
                }
#pragma unroll
                for (int nt = 0; nt < 4; ++nt)
#pragma unroll
                    for (int rg = 0; rg < 4; ++rg)
                        o_acc[qh][nt][rg] *= alpha[rg];

                // PV (wave-internal P exchange; no barrier needed)
                bf16x8 pf[2];
#pragma unroll
                for (int kk = 0; kk < 2; ++kk)
                    pf[kk] = *(const bf16x8*)&Ps[(w*32 + qh*16 + l16)*68 + kk*32 + quad*8];
#pragma unroll
                for (int nt = 0; nt < 4; ++nt)
#pragma unroll
                    for (int kk = 0; kk < 2; ++kk) {
                        bf16x8 vf = *(const bf16x8*)&Vts[(nt*16 + l16)*72 + kk*32 + quad*8];
                        o_acc[qh][nt] = __builtin_amdgcn_mfma_f32_16x16x32_bf16(
                            pf[kk], vf, o_acc[qh][nt], 0, 0, 0);
                    }
            }
        }

        // epilogue
#pragma unroll
        for (int qh = 0; qh < 2; ++qh)
#pragma unroll
            for (int nt = 0; nt < 4; ++nt)
#pragma unroll
                for (int rg = 0; rg < 4; ++rg) {
                    int m = w*32 + qh*16 + quad*4 + rg;
                    OA[((size_t)b*NS + s0 + m)*ND + h*NDH + nt*16 + l16] =
                        f2bf(o_acc[qh][nt][rg] / lsum[qh][rg]);
                }
    } else {
        // ---------------- sparse path (fp32 scalar, bf16 inputs) ----------
        const int r   = lane & 15;
        const int cg  = lane >> 4;
#pragma unroll
        for (int qh = 0; qh < 2; ++qh) {
            const int row = w*32 + qh*16 + r;

            float qreg[64];
            {
                const ushort* qp = Qh + (size_t)(s0 + row) * NDH;
#pragma unroll
                for (int c = 0; c < 8; ++c) {
                    union { bf16x8 v; ushort s[8]; } qv;
                    qv.v = *(const bf16x8*)(qp + c*8);
#pragma unroll
                    for (int j = 0; j < 8; ++j) qreg[c*8 + j] = bf2f(qv.s[j]);
                }
            }

            float sc[8];
#pragma unroll
            for (int jj = 0; jj < 8; ++jj) {
                int j  = cg*8 + jj;
                int mv = pimask[(size_t)(s0+row)*NKSP + j];
                if (mv) {
                    int kv = pidx[(size_t)(s0+row)*NKSP + j];
                    const ushort* krow = &Kh[(size_t)kv * NDH];
                    float acc = 0.f;
#pragma unroll
                    for (int c = 0; c < 8; ++c) {
                        union { bf16x8 v; ushort s[8]; } kk;
                        kk.v = *(const bf16x8*)(krow + c*8);
#pragma unroll
                        for (int jb = 0; jb < 8; ++jb)
                            acc = fmaf(qreg[c*8 + jb], bf2f(kk.s[jb]), acc);
                    }
                    sc[jj] = acc * SCALE;
                } else {
                    sc[jj] = -INFINITY;
                }
            }
            float mt = sc[0];
#pragma unroll
            for (int jj = 1; jj < 8; ++jj) mt = fmaxf(mt, sc[jj]);
            mt = fmaxf(mt, __shfl_xor(mt, 16));
            mt = fmaxf(mt, __shfl_xor(mt, 32));

            float psum = 0.f;
#pragma unroll
            for (int jj = 0; jj < 8; ++jj) {
                float p = __expf(sc[jj] - mt);
                psum += p;
                Ps[row * 68 + cg*8 + jj] = f2bf(p);
            }
            psum += __shfl_xor(psum, 16);
            psum += __shfl_xor(psum, 32);

            float o[16];
#pragma unroll
            for (int i = 0; i < 16; ++i) o[i] = 0.f;

            for (int j = 0; j < 32; ++j) {
                float p = bf2f(Ps[row * 68 + j]);
                if (p != 0.f) {
                    int kv = pidx[(size_t)(s0+row)*NKSP + j];
                    const ushort* vrow = &Vh[(size_t)kv * NDH + cg*16];
#pragma unroll
                    for (int c = 0; c < 2; ++c) {
                        union { bf16x8 v; ushort s[8]; } vv;
                        vv.v = *(const bf16x8*)(vrow + c*8);
#pragma unroll
                        for (int jb = 0; jb < 8; ++jb)
                            o[c*8 + jb] = fmaf(p, bf2f(vv.s[jb]), o[c*8 + jb]);
                    }
                }
            }

            float inv = 1.f / psum;
            ushort* op = OA + ((size_t)b*NS + s0 + row)*ND + h*NDH + cg*16;
#pragma unroll
            for (int i4 = 0; i4 < 4; ++i4) {
                ushort4 v;
                v.x = f2bf(o[i4*4+0]*inv); v.y = f2bf(o[i4*4+1]*inv);
                v.z = f2bf(o[i4*4+2]*inv); v.w = f2bf(o[i4*4+3]*inv);
                *(ushort4*)(op + i4*4) = v;
            }
        }
    }
}

// ---------------------------------------------------------------------------
extern "C" void kernel_launch(void* const* d_in, const int* in_sizes, int n_in,
                              void* d_out, int out_size, void* d_ws, size_t ws_size,
                              hipStream_t stream)
{
    const float* x      = (const float*)d_in[0];
    const int*   pmask  = (const int*)  d_in[1];
    const int*   pidx   = (const int*)  d_in[2];
    const int*   pimask = (const int*)  d_in[3];
    const float* u_prev = (const float*)d_in[4];
    const float* Wq     = (const float*)d_in[5];
    const float* bq     = (const float*)d_in[6];
    const float* Wk     = (const float*)d_in[7];
    const float* bk     = (const float*)d_in[8];
    const float* Wv     = (const float*)d_in[9];
    const float* bv     = (const float*)d_in[10];
    const float* Wo     = (const float*)d_in[11];
    const float* bo     = (const float*)d_in[12];
    float* out = (float*)d_out;

    const size_t QSZ = (size_t)NB * NH * NS * NDH;   // 4,194,304 elements
    const size_t WSZ = (size_t)ND * ND;              // 1,048,576 elements
    ushort* xb  = (ushort*)d_ws;        // bf16 x              (8 MB)
    ushort* Qw  = xb  + QSZ;            // bf16 Q (b,h,s,dh)   (8 MB)
    ushort* Kw  = Qw  + QSZ;            // bf16 K              (8 MB)
    ushort* Vw  = Kw  + QSZ;            // bf16 V              (8 MB)
    ushort* Vtw = Vw  + QSZ;            // bf16 V^T (b,h,dh,s) (8 MB)
    ushort* Awb = Vtw + QSZ;            // bf16 attn out       (8 MB)
    ushort* Wqb = Awb + QSZ;            // bf16 weights (2 MB each)
    ushort* Wkb = Wqb + WSZ;
    ushort* Wvb = Wkb + WSZ;
    ushort* Wob = Wvb + WSZ;
    u64*    bmw = (u64*)(Wob + WSZ);    // packed mask (128 KB)

    f2bf_multi<<<dim3(4096, 5), 256, 0, stream>>>(
        x, Wq, Wk, Wv, Wo, xb, Wqb, Wkb, Wvb, Wob);
    pack_mask<<<(NS*NS/64)/4, 256, 0, stream>>>(pmask, bmw);

    gemm_qkv<<<dim3(24, 32), 256, 0, stream>>>(
        xb, Wqb, Wkb, Wvb, bq, bk, bv, Qw, Kw, Vw);

    transpose_v<<<dim3(NS/64, NB*NH), 256, 0, stream>>>(Vw, Vtw);

    attn_kernel<<<dim3(NS/128, NH, NB), 256, 0, stream>>>(
        Qw, Kw, Vw, Vtw, bmw, pidx, pimask, u_prev, Awb);

    gemm_out<<<dim3(ND/128, (NB*NS)/64), 256, 0, stream>>>(Awb, Wob, bo, out);
}